// Round 1
// baseline (302.696 us; speedup 1.0000x reference)
//
#include <hip/hip_runtime.h>

// out = atoms_x - segment_mean(atoms_x, graph_batch)[graph_batch]
// graph_batch is SORTED -> each molecule's atoms are contiguous (~40/mol).

#define M_MOLS 200000

static constexpr int CPT = 8;  // atoms per thread, segment-sum pass
static constexpr int APT = 4;  // atoms per thread, subtract pass

#define FLUSH_SUMS()                                   \
  do {                                                 \
    atomicAdd(&sums[(size_t)cur * 4 + 0], sx);         \
    atomicAdd(&sums[(size_t)cur * 4 + 1], sy);         \
    atomicAdd(&sums[(size_t)cur * 4 + 2], sz);         \
    atomicAdd(&sums[(size_t)cur * 4 + 3], sc);         \
  } while (0)

// GS = element stride of the id array (1 = int32, 2 = int64 low word fallback)
template <int GS>
__global__ void seg_sum_kernel(const float* __restrict__ x,
                               const int* __restrict__ gb,
                               float* __restrict__ sums, int n) {
  long long t = (long long)blockIdx.x * blockDim.x + threadIdx.x;
  long long base = t * CPT;
  if (base >= n) return;

  if (base + CPT <= n) {
    // ---- fast path: fully unrolled, register-resident ----
    float f[CPT * 3];
    const float4* xv = reinterpret_cast<const float4*>(x + base * 3);
#pragma unroll
    for (int j = 0; j < CPT * 3 / 4; ++j) {
      float4 v = xv[j];
      f[j * 4 + 0] = v.x; f[j * 4 + 1] = v.y;
      f[j * 4 + 2] = v.z; f[j * 4 + 3] = v.w;
    }
    int ids[CPT];
    if constexpr (GS == 1) {
      const int4* gv = reinterpret_cast<const int4*>(gb + base);
#pragma unroll
      for (int j = 0; j < CPT / 4; ++j) {
        int4 g = gv[j];
        ids[j * 4 + 0] = g.x; ids[j * 4 + 1] = g.y;
        ids[j * 4 + 2] = g.z; ids[j * 4 + 3] = g.w;
      }
    } else {
#pragma unroll
      for (int j = 0; j < CPT; ++j) ids[j] = gb[(base + j) * GS];
    }

    int cur = ids[0];
    float sx = 0.f, sy = 0.f, sz = 0.f, sc = 0.f;
#pragma unroll
    for (int j = 0; j < CPT; ++j) {
      if (ids[j] != cur) {
        FLUSH_SUMS();
        cur = ids[j];
        sx = sy = sz = sc = 0.f;
      }
      sx += f[j * 3 + 0];
      sy += f[j * 3 + 1];
      sz += f[j * 3 + 2];
      sc += 1.f;
    }
    FLUSH_SUMS();
  } else {
    // ---- scalar tail ----
    int cur = gb[base * GS];
    float sx = 0.f, sy = 0.f, sz = 0.f, sc = 0.f;
    for (long long i = base; i < n; ++i) {
      int id = gb[i * GS];
      if (id != cur) {
        FLUSH_SUMS();
        cur = id;
        sx = sy = sz = sc = 0.f;
      }
      sx += x[i * 3 + 0];
      sy += x[i * 3 + 1];
      sz += x[i * 3 + 2];
      sc += 1.f;
    }
    FLUSH_SUMS();
  }
}

__global__ void mean_kernel(float* __restrict__ sums, int m) {
  int i = blockIdx.x * blockDim.x + threadIdx.x;
  if (i >= m) return;
  float4 s = reinterpret_cast<float4*>(sums)[i];
  float inv = (s.w > 0.f) ? (1.f / s.w) : 0.f;
  s.x *= inv; s.y *= inv; s.z *= inv; s.w = 0.f;
  reinterpret_cast<float4*>(sums)[i] = s;
}

template <int GS>
__global__ void subtract_kernel(const float* __restrict__ x,
                                const int* __restrict__ gb,
                                const float* __restrict__ mean,
                                float* __restrict__ out, int n) {
  long long t = (long long)blockIdx.x * blockDim.x + threadIdx.x;
  long long base = t * APT;
  if (base >= n) return;

  if (base + APT <= n) {
    int i0, i1, i2, i3;
    if constexpr (GS == 1) {
      int4 g = *reinterpret_cast<const int4*>(gb + base);
      i0 = g.x; i1 = g.y; i2 = g.z; i3 = g.w;
    } else {
      i0 = gb[(base + 0) * GS];
      i1 = gb[(base + 1) * GS];
      i2 = gb[(base + 2) * GS];
      i3 = gb[(base + 3) * GS];
    }
    const float4* xv = reinterpret_cast<const float4*>(x + base * 3);
    float4 v0 = xv[0], v1 = xv[1], v2 = xv[2];
    float4 m0 = *reinterpret_cast<const float4*>(mean + (size_t)i0 * 4);
    float4 m1 = *reinterpret_cast<const float4*>(mean + (size_t)i1 * 4);
    float4 m2 = *reinterpret_cast<const float4*>(mean + (size_t)i2 * 4);
    float4 m3 = *reinterpret_cast<const float4*>(mean + (size_t)i3 * 4);
    float4 o0, o1, o2;
    o0.x = v0.x - m0.x; o0.y = v0.y - m0.y; o0.z = v0.z - m0.z;
    o0.w = v0.w - m1.x;
    o1.x = v1.x - m1.y; o1.y = v1.y - m1.z;
    o1.z = v1.z - m2.x; o1.w = v1.w - m2.y;
    o2.x = v2.x - m2.z;
    o2.y = v2.y - m3.x; o2.z = v2.z - m3.y; o2.w = v2.w - m3.z;
    float4* ov = reinterpret_cast<float4*>(out + base * 3);
    ov[0] = o0; ov[1] = o1; ov[2] = o2;
  } else {
    for (long long i = base; i < n; ++i) {
      int id = gb[i * GS];
      out[i * 3 + 0] = x[i * 3 + 0] - mean[(size_t)id * 4 + 0];
      out[i * 3 + 1] = x[i * 3 + 1] - mean[(size_t)id * 4 + 1];
      out[i * 3 + 2] = x[i * 3 + 2] - mean[(size_t)id * 4 + 2];
    }
  }
}

extern "C" void kernel_launch(void* const* d_in, const int* in_sizes, int n_in,
                              void* d_out, int out_size, void* d_ws, size_t ws_size,
                              hipStream_t stream) {
  const float* x = (const float*)d_in[0];
  const int* gb = (const int*)d_in[1];
  float* out = (float*)d_out;
  float* sums = (float*)d_ws;  // [M_MOLS][4] = {sx, sy, sz, count} -> then mean

  const int n = in_sizes[0] / 3;  // atoms

  // 1) zero the per-molecule accumulators (harness does NOT re-poison ws)
  hipMemsetAsync(sums, 0, (size_t)M_MOLS * 4 * sizeof(float), stream);

  // 2) segment sum (sorted-aware, register run-accumulation + boundary atomics)
  {
    long long threads = (n + CPT - 1) / CPT;
    int blocks = (int)((threads + 255) / 256);
    seg_sum_kernel<1><<<blocks, 256, 0, stream>>>(x, gb, sums, n);
  }

  // 3) mean = sum / max(count, 1) (in place; empty mols -> 0)
  {
    int blocks = (M_MOLS + 255) / 256;
    mean_kernel<<<blocks, 256, 0, stream>>>(sums, M_MOLS);
  }

  // 4) out = x - mean[gb]
  {
    long long threads = (n + APT - 1) / APT;
    int blocks = (int)((threads + 255) / 256);
    subtract_kernel<1><<<blocks, 256, 0, stream>>>(x, gb, sums, out, n);
  }
}

// Round 2
// 68.800 us; speedup vs baseline: 4.3997x; 4.3997x over previous
//
#include <hip/hip_runtime.h>

// out = atoms_x - segment_mean(atoms_x, graph_batch)[graph_batch]
// graph_batch is SORTED. Fused single-pass: per-block LDS segment sums
// (slot = id - first_id_in_chunk), halo scans complete edge molecules,
// subtract from register-resident coords. No global atomics, no workspace.

static constexpr int TPB   = 256;
static constexpr int CPT   = 8;            // atoms per thread
static constexpr int CHUNK = TPB * CPT;    // 2048 atoms per block
static constexpr int SLOTS = 2048;         // max id-span per chunk

__global__ __launch_bounds__(TPB) void fused_center_kernel(
    const float* __restrict__ x, const int* __restrict__ gb,
    float* __restrict__ out, int n) {
  __shared__ float sums[SLOTS * 4];  // {sx, sy, sz, cnt} per slot

  const long long cs = (long long)blockIdx.x * CHUNK;
  const long long ce = (cs + CHUNK < (long long)n) ? cs + CHUNK : (long long)n;
  const int fid = gb[cs];
  const int lid = gb[ce - 1];
  const int span = lid - fid + 1;

  if (span > SLOTS) {
    // Pathological id-sparsity (huge empty-molecule gaps). Correct, serial,
    // never triggered by this data distribution. Uniform branch: all threads
    // see the same span, so returning before any __syncthreads is safe.
    if (threadIdx.x == 0) {
      long long i = cs;
      while (i < ce) {
        int id = gb[i];
        long long rs = i; while (rs > 0 && gb[rs - 1] == id) --rs;
        long long re = i; while (re < n && gb[re] == id) ++re;
        float sx = 0.f, sy = 0.f, sz = 0.f;
        for (long long k = rs; k < re; ++k) {
          sx += x[k * 3 + 0]; sy += x[k * 3 + 1]; sz += x[k * 3 + 2];
        }
        float inv = 1.f / (float)(re - rs);
        float mx = sx * inv, my = sy * inv, mz = sz * inv;
        long long we = (re < ce) ? re : ce;
        for (long long k = i; k < we; ++k) {
          out[k * 3 + 0] = x[k * 3 + 0] - mx;
          out[k * 3 + 1] = x[k * 3 + 1] - my;
          out[k * 3 + 2] = x[k * 3 + 2] - mz;
        }
        i = we;
      }
    }
    return;
  }

  // zero only the slots this chunk can touch
  for (int i = threadIdx.x; i < span * 4; i += TPB) sums[i] = 0.f;
  __syncthreads();

  const long long base = cs + (long long)threadIdx.x * CPT;
  const bool full = (base + CPT <= ce);

  float f[CPT * 3];
  int ids[CPT];

  if (full) {
    // ---- fast path: fully unrolled, register-resident ----
    const float4* xv = reinterpret_cast<const float4*>(x + base * 3);
#pragma unroll
    for (int j = 0; j < CPT * 3 / 4; ++j) {
      float4 v = xv[j];
      f[j * 4 + 0] = v.x; f[j * 4 + 1] = v.y;
      f[j * 4 + 2] = v.z; f[j * 4 + 3] = v.w;
    }
    const int4* gv = reinterpret_cast<const int4*>(gb + base);
#pragma unroll
    for (int j = 0; j < CPT / 4; ++j) {
      int4 g = gv[j];
      ids[j * 4 + 0] = g.x; ids[j * 4 + 1] = g.y;
      ids[j * 4 + 2] = g.z; ids[j * 4 + 3] = g.w;
    }

    int cur = ids[0];
    float sx = 0.f, sy = 0.f, sz = 0.f, sc = 0.f;
#pragma unroll
    for (int j = 0; j < CPT; ++j) {
      if (ids[j] != cur) {
        int s = (cur - fid) * 4;
        atomicAdd(&sums[s + 0], sx); atomicAdd(&sums[s + 1], sy);
        atomicAdd(&sums[s + 2], sz); atomicAdd(&sums[s + 3], sc);
        cur = ids[j]; sx = sy = sz = sc = 0.f;
      }
      sx += f[j * 3 + 0]; sy += f[j * 3 + 1]; sz += f[j * 3 + 2]; sc += 1.f;
    }
    {
      int s = (cur - fid) * 4;
      atomicAdd(&sums[s + 0], sx); atomicAdd(&sums[s + 1], sy);
      atomicAdd(&sums[s + 2], sz); atomicAdd(&sums[s + 3], sc);
    }
  } else if (base < ce) {
    // tail atoms (last block only)
    for (long long i = base; i < ce; ++i) {
      int s = (gb[i] - fid) * 4;
      atomicAdd(&sums[s + 0], x[i * 3 + 0]);
      atomicAdd(&sums[s + 1], x[i * 3 + 1]);
      atomicAdd(&sums[s + 2], x[i * 3 + 2]);
      atomicAdd(&sums[s + 3], 1.f);
    }
  }

  // ---- halos: complete the edge molecules (owned redundantly, no comms) ----
  if (cs > 0 && threadIdx.x < 64) {
    float hx = 0.f, hy = 0.f, hz = 0.f, hc = 0.f;
    long long i = cs - 1 - (long long)threadIdx.x;
    while (i >= 0 && gb[i] == fid) {
      hx += x[i * 3 + 0]; hy += x[i * 3 + 1]; hz += x[i * 3 + 2]; hc += 1.f;
      i -= 64;
    }
    if (hc > 0.f) {
      atomicAdd(&sums[0], hx); atomicAdd(&sums[1], hy);
      atomicAdd(&sums[2], hz); atomicAdd(&sums[3], hc);
    }
  }
  if (ce < (long long)n && threadIdx.x >= 64 && threadIdx.x < 128) {
    int lane = threadIdx.x - 64;
    float hx = 0.f, hy = 0.f, hz = 0.f, hc = 0.f;
    long long i = ce + lane;
    while (i < (long long)n && gb[i] == lid) {
      hx += x[i * 3 + 0]; hy += x[i * 3 + 1]; hz += x[i * 3 + 2]; hc += 1.f;
      i += 64;
    }
    if (hc > 0.f) {
      int s = (lid - fid) * 4;
      atomicAdd(&sums[s + 0], hx); atomicAdd(&sums[s + 1], hy);
      atomicAdd(&sums[s + 2], hz); atomicAdd(&sums[s + 3], hc);
    }
  }
  __syncthreads();

  // ---- sums -> means (in LDS) ----
  for (int s = threadIdx.x; s < span; s += TPB) {
    float c = sums[s * 4 + 3];
    if (c > 0.f) {
      float inv = 1.f / c;
      sums[s * 4 + 0] *= inv; sums[s * 4 + 1] *= inv; sums[s * 4 + 2] *= inv;
    }
  }
  __syncthreads();

  // ---- subtract + write ----
  if (full) {
    float o[CPT * 3];
#pragma unroll
    for (int j = 0; j < CPT; ++j) {
      int s = (ids[j] - fid) * 4;
      o[j * 3 + 0] = f[j * 3 + 0] - sums[s + 0];
      o[j * 3 + 1] = f[j * 3 + 1] - sums[s + 1];
      o[j * 3 + 2] = f[j * 3 + 2] - sums[s + 2];
    }
    float4* ov = reinterpret_cast<float4*>(out + base * 3);
#pragma unroll
    for (int j = 0; j < CPT * 3 / 4; ++j)
      ov[j] = make_float4(o[j * 4 + 0], o[j * 4 + 1], o[j * 4 + 2], o[j * 4 + 3]);
  } else if (base < ce) {
    for (long long i = base; i < ce; ++i) {
      int s = (gb[i] - fid) * 4;
      out[i * 3 + 0] = x[i * 3 + 0] - sums[s + 0];
      out[i * 3 + 1] = x[i * 3 + 1] - sums[s + 1];
      out[i * 3 + 2] = x[i * 3 + 2] - sums[s + 2];
    }
  }
}

extern "C" void kernel_launch(void* const* d_in, const int* in_sizes, int n_in,
                              void* d_out, int out_size, void* d_ws, size_t ws_size,
                              hipStream_t stream) {
  const float* x = (const float*)d_in[0];
  const int* gb = (const int*)d_in[1];
  float* out = (float*)d_out;
  const int n = in_sizes[0] / 3;  // atoms

  int blocks = (int)(((long long)n + CHUNK - 1) / CHUNK);
  fused_center_kernel<<<blocks, TPB, 0, stream>>>(x, gb, out, n);
}